// Round 3
// baseline (198.595 us; speedup 1.0000x reference)
//
#include <hip/hip_runtime.h>

#define H 256
#define W 256
#define W4 (W / 4)             // 64 float4 per image row
#define OWID 250
#define NIMG 256               // B*D
#define BAND 10                // output rows per wave; 25*10 == 250 exactly
#define NBANDS 25
#define NBLK (NBANDS * NIMG)   // 6400 partials
#define ROWS_IN (BAND + 6)     // 16 input rows per band (static for every band)

__device__ __forceinline__ float4 f4zero() { return make_float4(0.f, 0.f, 0.f, 0.f); }

// s += n - o  (component-wise)
__device__ __forceinline__ void vacc(float4& s, const float4 n, const float4 o) {
    s.x += n.x - o.x; s.y += n.y - o.y; s.z += n.z - o.z; s.w += n.w - o.w;
}
// s += a*b - c*d  (component-wise)
__device__ __forceinline__ void vaccp(float4& s, const float4 a, const float4 b,
                                      const float4 c, const float4 d) {
    s.x += a.x * b.x - c.x * d.x;
    s.y += a.y * b.y - c.y * d.y;
    s.z += a.z * b.z - c.z * d.z;
    s.w += a.w * b.w - c.w * d.w;
}

// Horizontal 7-tap window sums from per-lane float4 vertical sums, via
// cross-lane shuffles (no LDS, no barriers). Lane t owns cols 4t..4t+3 and
// needs cols 4t+4..4t+7 (lane t+1) and 4t+8,4t+9 (lane t+2). Out-of-range
// lanes wrap (bpermute mod 64) to finite garbage feeding only masked cols.
#define HWIN(S, WA) do {                                        \
    float bx = __shfl_down(S.x, 1);                             \
    float by = __shfl_down(S.y, 1);                             \
    float bz = __shfl_down(S.z, 1);                             \
    float bw = __shfl_down(S.w, 1);                             \
    float cx = __shfl_down(S.x, 2);                             \
    float cy = __shfl_down(S.y, 2);                             \
    WA[0] = ((S.x + S.y) + (S.z + S.w)) + ((bx + by) + bz);     \
    WA[1] = WA[0] - S.x + bw;                                   \
    WA[2] = WA[1] - S.y + cx;                                   \
    WA[3] = WA[2] - S.z + cy;                                   \
} while (0)

__global__ __launch_bounds__(64, 4) void ssim_band_kernel(
    const float* __restrict__ X, const float* __restrict__ Y,
    float* __restrict__ partial)
{
    const int lane = threadIdx.x;   // 0..63, owns cols 4*lane..4*lane+3
    const int band = blockIdx.x;    // 0..24
    const int img  = blockIdx.y;    // 0..255
    const int r0 = band * BAND;

    const float4* Xp = (const float4*)X + ((size_t)img * H + r0) * W4 + lane;
    const float4* Yp = (const float4*)Y + ((size_t)img * H + r0) * W4 + lane;

    // 7-deep register history of raw x,y rows + running vertical raw sums.
    float4 xh[7], yh[7];
    float4 sx = f4zero(), sy = f4zero(), sxx = f4zero(), syy = f4zero(), sxy = f4zero();

    #pragma unroll
    for (int i = 0; i < 6; ++i) {
        float4 xv = Xp[i * W4];
        float4 yv = Yp[i * W4];
        xh[i] = xv; yh[i] = yv;
        vacc(sx, xv, f4zero());
        vacc(sy, yv, f4zero());
        vaccp(sxx, xv, xv, f4zero(), f4zero());
        vaccp(syy, yv, yv, f4zero(), f4zero());
        vaccp(sxy, xv, yv, f4zero(), f4zero());
    }

    float4 xn = Xp[6 * W4];
    float4 yn = Yp[6 * W4];

    // SSIM on RAW 7x7 sums: the 1/49, 1/2401 normalizations cancel in
    // (A1*A2)/(B1*B2). Constants pre-scaled by 2401.
    const float C1N  = 0.2401f;        // 1e-4 * 2401
    const float C2N  = 2.1609f;        // 9e-4 * 2401
    const float COV  = 49.0f / 48.0f;  // cov_norm
    const float COV2 = 2.0f * COV;
    float lsum = 0.0f;

    // Fully static: every band has exactly 16 input rows / 10 output rows.
    #pragma unroll
    for (int r = 6; r < ROWS_IN; ++r) {
        float4 xf, yf;
        if (r + 1 < ROWS_IN) {               // compile-time after unroll
            xf = Xp[(r + 1) * W4];
            yf = Yp[(r + 1) * W4];
        }
        const int slot = r % 7;              // static after unroll
        const float4 xo = xh[slot], yo = yh[slot];
        vacc(sx, xn, xo);
        vacc(sy, yn, yo);
        vaccp(sxx, xn, xn, xo, xo);
        vaccp(syy, yn, yn, yo, yo);
        vaccp(sxy, xn, yn, xo, yo);
        xh[slot] = xn; yh[slot] = yn;

        float wx[4], wy[4], wxx[4], wyy[4], wxy[4];
        HWIN(sx,  wx);
        HWIN(sy,  wy);
        HWIN(sxx, wxx);
        HWIN(syy, wyy);
        HWIN(sxy, wxy);

        #pragma unroll
        for (int s = 0; s < 4; ++s) {
            const float SX = wx[s], SY = wy[s];
            const float t1 = SX * SY;
            const float t2 = SX * SX;
            const float t3 = SY * SY;
            const float A1 = 2.0f * t1 + C1N;
            const float B1 = (t2 + t3) + C1N;
            const float A2 = COV2 * (49.0f * wxy[s] - t1) + C2N;
            const float B2 = COV * (49.0f * (wxx[s] + wyy[s]) - (t2 + t3)) + C2N;
            const float S = (A1 * A2) * __builtin_amdgcn_rcpf(B1 * B2);
            if (4 * lane + s < OWID) lsum += S;   // mask cols >= 250
        }
        xn = xf; yn = yf;
    }

    // Wave reduction -> one partial per block.
    #pragma unroll
    for (int off = 32; off > 0; off >>= 1)
        lsum += __shfl_down(lsum, off, 64);
    if (lane == 0) partial[img * NBANDS + band] = lsum;
}

__global__ __launch_bounds__(256) void ssim_reduce_kernel(
    const float* __restrict__ partial, float* __restrict__ out)
{
    const int tid = threadIdx.x;
    double acc = 0.0;
    for (int i = tid; i < NBLK; i += 256)
        acc += (double)partial[i];
    #pragma unroll
    for (int off = 32; off > 0; off >>= 1)
        acc += __shfl_down(acc, off, 64);
    __shared__ double wsumd[4];
    if ((tid & 63) == 0) wsumd[tid >> 6] = acc;
    __syncthreads();
    if (tid == 0) {
        double total = wsumd[0] + wsumd[1] + wsumd[2] + wsumd[3];
        float loss = (float)(1.0 - total / 16000000.0);
        out[0] = loss; out[1] = loss; out[2] = loss; out[3] = loss;
    }
}

extern "C" void kernel_launch(void* const* d_in, const int* in_sizes, int n_in,
                              void* d_out, int out_size, void* d_ws, size_t ws_size,
                              hipStream_t stream) {
    const float* X = (const float*)d_in[0];
    const float* Y = (const float*)d_in[1];
    // d_in[2] is the uniform 7x7 filter (1/49 everywhere) — constant-folded.
    float* out = (float*)d_out;
    float* partial = (float*)d_ws;   // 6400 floats = 25.6 KB

    hipLaunchKernelGGL(ssim_band_kernel, dim3(NBANDS, NIMG), dim3(64), 0, stream,
                       X, Y, partial);
    hipLaunchKernelGGL(ssim_reduce_kernel, dim3(1), dim3(256), 0, stream,
                       partial, out);
}

// Round 4
// 163.297 us; speedup vs baseline: 1.2162x; 1.2162x over previous
//
#include <hip/hip_runtime.h>

#define H 256
#define W 256
#define W4 (W / 4)             // 64 float4 per image row
#define OWID 250
#define NIMG 256               // B*D
#define BAND 10                // output rows per wave; 25*10 == 250 exactly
#define NBANDS 25
#define NBLK (NBANDS * NIMG)   // 6400 partials
#define ROWS_IN (BAND + 6)     // 16 input rows per band (static for every band)

__device__ __forceinline__ float4 f4zero() { return make_float4(0.f, 0.f, 0.f, 0.f); }

// s += n - o  (component-wise)
__device__ __forceinline__ void vacc(float4& s, const float4 n, const float4 o) {
    s.x += n.x - o.x; s.y += n.y - o.y; s.z += n.z - o.z; s.w += n.w - o.w;
}
// s += a*b - c*d  (component-wise)
__device__ __forceinline__ void vaccp(float4& s, const float4 a, const float4 b,
                                      const float4 c, const float4 d) {
    s.x += a.x * b.x - c.x * d.x;
    s.y += a.y * b.y - c.y * d.y;
    s.z += a.z * b.z - c.z * d.z;
    s.w += a.w * b.w - c.w * d.w;
}

// Horizontal 7-tap window sums from per-lane float4 vertical sums via
// cross-lane shuffles (no LDS, no barriers). Lane t owns cols 4t..4t+3 and
// needs cols 4t+4..4t+7 (lane t+1) and 4t+8,4t+9 (lane t+2). 4 shuffles per
// moment: the lane+1 x+y+z partial comes over pre-combined. Out-of-range
// lanes wrap (bpermute mod 64) to finite garbage feeding only masked cols.
#define HWIN(S, WA) do {                                        \
    float sxyz = (S.x + S.y) + S.z;                             \
    float b3 = __shfl_down(sxyz, 1);                            \
    float bw = __shfl_down(S.w, 1);                             \
    float cx = __shfl_down(S.x, 2);                             \
    float cy = __shfl_down(S.y, 2);                             \
    WA[0] = (sxyz + S.w) + b3;                                  \
    WA[1] = WA[0] - S.x + bw;                                   \
    WA[2] = WA[1] - S.y + cx;                                   \
    WA[3] = WA[2] - S.z + cy;                                   \
} while (0)

// NOTE: no min-waves hint. R3's __launch_bounds__(64,4) clamped the allocator
// to 64 VGPRs (live set ~110) -> 110 MB scratch spill traffic, 94 us. Plain
// bound lands ~100 VGPR <= 128 -> 4 waves/SIMD bracket, zero spill.
__global__ __launch_bounds__(64) void ssim_band_kernel(
    const float* __restrict__ X, const float* __restrict__ Y,
    float* __restrict__ partial)
{
    const int lane = threadIdx.x;   // 0..63, owns cols 4*lane..4*lane+3
    const int band = blockIdx.x;    // 0..24
    const int img  = blockIdx.y;    // 0..255
    const int r0 = band * BAND;

    const float4* Xp = (const float4*)X + ((size_t)img * H + r0) * W4 + lane;
    const float4* Yp = (const float4*)Y + ((size_t)img * H + r0) * W4 + lane;

    // 7-deep register history of raw x,y rows + running vertical raw sums.
    float4 xh[7], yh[7];
    float4 sx = f4zero(), sy = f4zero(), sxx = f4zero(), syy = f4zero(), sxy = f4zero();

    #pragma unroll
    for (int i = 0; i < 6; ++i) {
        float4 xv = Xp[i * W4];
        float4 yv = Yp[i * W4];
        xh[i] = xv; yh[i] = yv;
        vacc(sx, xv, f4zero());
        vacc(sy, yv, f4zero());
        vaccp(sxx, xv, xv, f4zero(), f4zero());
        vaccp(syy, yv, yv, f4zero(), f4zero());
        vaccp(sxy, xv, yv, f4zero(), f4zero());
    }

    float4 xn = Xp[6 * W4];
    float4 yn = Yp[6 * W4];

    // SSIM on RAW 7x7 sums: the 1/49, 1/2401 normalizations cancel in
    // (A1*A2)/(B1*B2). Constants pre-scaled by 2401.
    const float C1N  = 0.2401f;        // 1e-4 * 2401
    const float C2N  = 2.1609f;        // 9e-4 * 2401
    const float COV  = 49.0f / 48.0f;  // cov_norm
    const float COV2 = 2.0f * COV;
    float lsum = 0.0f;

    // Fully static: every band has exactly 16 input rows / 10 output rows.
    #pragma unroll
    for (int r = 6; r < ROWS_IN; ++r) {
        float4 xf, yf;
        if (r + 1 < ROWS_IN) {               // compile-time after unroll
            xf = Xp[(r + 1) * W4];
            yf = Yp[(r + 1) * W4];
        }
        const int slot = r % 7;              // static after unroll
        const float4 xo = xh[slot], yo = yh[slot];
        vacc(sx, xn, xo);
        vacc(sy, yn, yo);
        vaccp(sxx, xn, xn, xo, xo);
        vaccp(syy, yn, yn, yo, yo);
        vaccp(sxy, xn, yn, xo, yo);
        xh[slot] = xn; yh[slot] = yn;

        float wx[4], wy[4], wxx[4], wyy[4], wxy[4];
        HWIN(sx,  wx);
        HWIN(sy,  wy);
        HWIN(sxx, wxx);
        HWIN(syy, wyy);
        HWIN(sxy, wxy);

        #pragma unroll
        for (int s = 0; s < 4; ++s) {
            const float SX = wx[s], SY = wy[s];
            const float t1 = SX * SY;
            const float t2 = SX * SX;
            const float t3 = SY * SY;
            const float A1 = 2.0f * t1 + C1N;
            const float B1 = (t2 + t3) + C1N;
            const float A2 = COV2 * (49.0f * wxy[s] - t1) + C2N;
            const float B2 = COV * (49.0f * (wxx[s] + wyy[s]) - (t2 + t3)) + C2N;
            const float S = (A1 * A2) * __builtin_amdgcn_rcpf(B1 * B2);
            if (4 * lane + s < OWID) lsum += S;   // mask cols >= 250
        }
        xn = xf; yn = yf;
    }

    // Wave reduction -> one partial per block.
    #pragma unroll
    for (int off = 32; off > 0; off >>= 1)
        lsum += __shfl_down(lsum, off, 64);
    if (lane == 0) partial[img * NBANDS + band] = lsum;
}

__global__ __launch_bounds__(256) void ssim_reduce_kernel(
    const float* __restrict__ partial, float* __restrict__ out)
{
    const int tid = threadIdx.x;
    double acc = 0.0;
    for (int i = tid; i < NBLK; i += 256)
        acc += (double)partial[i];
    #pragma unroll
    for (int off = 32; off > 0; off >>= 1)
        acc += __shfl_down(acc, off, 64);
    __shared__ double wsumd[4];
    if ((tid & 63) == 0) wsumd[tid >> 6] = acc;
    __syncthreads();
    if (tid == 0) {
        double total = wsumd[0] + wsumd[1] + wsumd[2] + wsumd[3];
        float loss = (float)(1.0 - total / 16000000.0);
        out[0] = loss; out[1] = loss; out[2] = loss; out[3] = loss;
    }
}

extern "C" void kernel_launch(void* const* d_in, const int* in_sizes, int n_in,
                              void* d_out, int out_size, void* d_ws, size_t ws_size,
                              hipStream_t stream) {
    const float* X = (const float*)d_in[0];
    const float* Y = (const float*)d_in[1];
    // d_in[2] is the uniform 7x7 filter (1/49 everywhere) — constant-folded.
    float* out = (float*)d_out;
    float* partial = (float*)d_ws;   // 6400 floats = 25.6 KB

    hipLaunchKernelGGL(ssim_band_kernel, dim3(NBANDS, NIMG), dim3(64), 0, stream,
                       X, Y, partial);
    hipLaunchKernelGGL(ssim_reduce_kernel, dim3(1), dim3(256), 0, stream,
                       partial, out);
}

// Round 5
// 160.788 us; speedup vs baseline: 1.2351x; 1.0156x over previous
//
#include <hip/hip_runtime.h>

#define H 256
#define W 256
#define W4 (W / 4)             // 64 float4 per image row
#define OWID 250
#define NIMG 256               // B*D
#define BAND 10                // output rows per wave; 25*10 == 250 exactly
#define NBANDS 25
#define NBLK (NBANDS * NIMG)   // 6400 partials
#define ROWS_IN (BAND + 6)     // 16 input rows per band (static for every band)
#define WPB 4                  // waves (images) per workgroup

__device__ __forceinline__ float4 f4zero() { return make_float4(0.f, 0.f, 0.f, 0.f); }

// s += n - o  (component-wise)
__device__ __forceinline__ void vacc(float4& s, const float4 n, const float4 o) {
    s.x += n.x - o.x; s.y += n.y - o.y; s.z += n.z - o.z; s.w += n.w - o.w;
}
// s += a*b - c*d  (component-wise)
__device__ __forceinline__ void vaccp(float4& s, const float4 a, const float4 b,
                                      const float4 c, const float4 d) {
    s.x += a.x * b.x - c.x * d.x;
    s.y += a.y * b.y - c.y * d.y;
    s.z += a.z * b.z - c.z * d.z;
    s.w += a.w * b.w - c.w * d.w;
}

// Horizontal 7-tap window sums from per-lane float4 vertical sums via
// cross-lane shuffles (no LDS, no barriers). Lane t owns cols 4t..4t+3 and
// needs cols 4t+4..4t+7 (lane t+1) and 4t+8,4t+9 (lane t+2). 4 shuffles per
// moment: the lane+1 x+y+z partial comes over pre-combined. Out-of-range
// lanes wrap (bpermute mod 64) to finite garbage feeding only masked cols.
#define HWIN(S, WA) do {                                        \
    float sxyz = (S.x + S.y) + S.z;                             \
    float b3 = __shfl_down(sxyz, 1);                            \
    float bw = __shfl_down(S.w, 1);                             \
    float cx = __shfl_down(S.x, 2);                             \
    float cy = __shfl_down(S.y, 2);                             \
    WA[0] = (sxyz + S.w) + b3;                                  \
    WA[1] = WA[0] - S.x + bw;                                   \
    WA[2] = WA[1] - S.y + cx;                                   \
    WA[3] = WA[2] - S.z + cy;                                   \
} while (0)

// 256-thread workgroups of 4 INDEPENDENT band-waves (no barriers): R2/R4
// showed single-wave workgroups cap residency at ~6 waves/CU (18% occ, 32%
// VALUBusy); R1's 256-thread groups reached 41% occ. No min-waves hint:
// R3's (64,4) clamp to 64 VGPR caused 110 MB of scratch spill.
__global__ __launch_bounds__(256) void ssim_band_kernel(
    const float* __restrict__ X, const float* __restrict__ Y,
    float* __restrict__ partial)
{
    const int lane = threadIdx.x & 63;        // owns cols 4*lane..4*lane+3
    const int wave = threadIdx.x >> 6;        // 0..3 -> image within group
    const int band = blockIdx.x;              // 0..24
    const int img  = blockIdx.y * WPB + wave; // 0..255
    const int r0 = band * BAND;

    const float4* Xp = (const float4*)X + ((size_t)img * H + r0) * W4 + lane;
    const float4* Yp = (const float4*)Y + ((size_t)img * H + r0) * W4 + lane;

    // 7-deep register history of raw x,y rows + running vertical raw sums.
    float4 xh[7], yh[7];
    float4 sx = f4zero(), sy = f4zero(), sxx = f4zero(), syy = f4zero(), sxy = f4zero();

    #pragma unroll
    for (int i = 0; i < 6; ++i) {
        float4 xv = Xp[i * W4];
        float4 yv = Yp[i * W4];
        xh[i] = xv; yh[i] = yv;
        vacc(sx, xv, f4zero());
        vacc(sy, yv, f4zero());
        vaccp(sxx, xv, xv, f4zero(), f4zero());
        vaccp(syy, yv, yv, f4zero(), f4zero());
        vaccp(sxy, xv, yv, f4zero(), f4zero());
    }

    float4 xn = Xp[6 * W4];
    float4 yn = Yp[6 * W4];

    // SSIM on RAW 7x7 sums: the 1/49, 1/2401 normalizations cancel in
    // (A1*A2)/(B1*B2). Constants pre-scaled by 2401.
    const float C1N  = 0.2401f;        // 1e-4 * 2401
    const float C2N  = 2.1609f;        // 9e-4 * 2401
    const float COV  = 49.0f / 48.0f;  // cov_norm
    const float COV2 = 2.0f * COV;
    float lsum = 0.0f;

    // Fully static: every band has exactly 16 input rows / 10 output rows.
    #pragma unroll
    for (int r = 6; r < ROWS_IN; ++r) {
        float4 xf, yf;
        if (r + 1 < ROWS_IN) {               // compile-time after unroll
            xf = Xp[(r + 1) * W4];
            yf = Yp[(r + 1) * W4];
        }
        const int slot = r % 7;              // static after unroll
        const float4 xo = xh[slot], yo = yh[slot];
        vacc(sx, xn, xo);
        vacc(sy, yn, yo);
        vaccp(sxx, xn, xn, xo, xo);
        vaccp(syy, yn, yn, yo, yo);
        vaccp(sxy, xn, yn, xo, yo);
        xh[slot] = xn; yh[slot] = yn;

        float wx[4], wy[4], wxx[4], wyy[4], wxy[4];
        HWIN(sx,  wx);
        HWIN(sy,  wy);
        HWIN(sxx, wxx);
        HWIN(syy, wyy);
        HWIN(sxy, wxy);

        #pragma unroll
        for (int s = 0; s < 4; ++s) {
            const float SX = wx[s], SY = wy[s];
            const float t1 = SX * SY;
            const float t2 = SX * SX;
            const float t3 = SY * SY;
            const float A1 = 2.0f * t1 + C1N;
            const float B1 = (t2 + t3) + C1N;
            const float A2 = COV2 * (49.0f * wxy[s] - t1) + C2N;
            const float B2 = COV * (49.0f * (wxx[s] + wyy[s]) - (t2 + t3)) + C2N;
            const float S = (A1 * A2) * __builtin_amdgcn_rcpf(B1 * B2);
            if (4 * lane + s < OWID) lsum += S;   // mask cols >= 250
        }
        xn = xf; yn = yf;
    }

    // Wave reduction -> one partial per wave.
    #pragma unroll
    for (int off = 32; off > 0; off >>= 1)
        lsum += __shfl_down(lsum, off, 64);
    if (lane == 0) partial[img * NBANDS + band] = lsum;
}

__global__ __launch_bounds__(1024) void ssim_reduce_kernel(
    const float* __restrict__ partial, float* __restrict__ out)
{
    const int tid = threadIdx.x;
    double acc = 0.0;
    for (int i = tid; i < NBLK; i += 1024)
        acc += (double)partial[i];
    #pragma unroll
    for (int off = 32; off > 0; off >>= 1)
        acc += __shfl_down(acc, off, 64);
    __shared__ double wsumd[16];
    if ((tid & 63) == 0) wsumd[tid >> 6] = acc;
    __syncthreads();
    if (tid == 0) {
        double total = 0.0;
        #pragma unroll
        for (int i = 0; i < 16; ++i) total += wsumd[i];
        float loss = (float)(1.0 - total / 16000000.0);
        out[0] = loss; out[1] = loss; out[2] = loss; out[3] = loss;
    }
}

extern "C" void kernel_launch(void* const* d_in, const int* in_sizes, int n_in,
                              void* d_out, int out_size, void* d_ws, size_t ws_size,
                              hipStream_t stream) {
    const float* X = (const float*)d_in[0];
    const float* Y = (const float*)d_in[1];
    // d_in[2] is the uniform 7x7 filter (1/49 everywhere) — constant-folded.
    float* out = (float*)d_out;
    float* partial = (float*)d_ws;   // 6400 floats = 25.6 KB

    hipLaunchKernelGGL(ssim_band_kernel, dim3(NBANDS, NIMG / WPB), dim3(256), 0,
                       stream, X, Y, partial);
    hipLaunchKernelGGL(ssim_reduce_kernel, dim3(1), dim3(1024), 0, stream,
                       partial, out);
}